// Round 8
// baseline (264.291 us; speedup 1.0000x reference)
//
#include <hip/hip_runtime.h>

typedef _Float16 hf;
typedef _Float16 half2v __attribute__((ext_vector_type(2)));
typedef _Float16 half8 __attribute__((ext_vector_type(8)));
typedef float f32x4 __attribute__((ext_vector_type(4)));

constexpr int Steps = 27;

// Static LDS carve-up (bytes), total 147,968 <= 160 KiB:
//   [0, 131072)       wlds: per-wave 16 KB = 16 frags (g=4,5 x ks=0..7) x 1 KB
//                     overlay during phase 1: xA [0,8192), hbuf [8192,24576)
//   [131072, 147456)  A ping-pong: 2 x (16x256) halfs
//   [147456, 147968)  red
constexpr int SM_TOTAL = 147968;
constexpr int SM_A = 131072;
constexpr int SM_RED = 147456;

__device__ __forceinline__ int aidx(int r, int k) {  // halfs, K=256 (A matrix)
  int blk = k >> 3;
  return r * 256 + (((blk ^ (r & 7)) & 31) << 3) + (k & 7);
}
__device__ __forceinline__ int hidx(int r, int k) {  // halfs, K=128 (phase-1 h buffers)
  int blk = k >> 3;
  return r * 128 + (((blk ^ (r & 15)) & 15) << 3) + (k & 7);
}
__device__ __forceinline__ int xidx(int r, int k) {  // halfs, K=64 (phase-1 x)
  int blk = k >> 3;
  return r * 64 + (((blk ^ (r & 7)) & 7) << 3) + (k & 7);
}
__device__ __forceinline__ float sigmoidf_(float x) { return 1.0f / (1.0f + __expf(-x)); }
__device__ __forceinline__ float tanh_(float x) { return 1.0f - 2.0f / (__expf(2.0f * x) + 1.0f); }

// one MFMA B-fragment (fp16) from an fp32 row-major matrix:
// element j of lane (c16,quad) = M[n0+c16][k0 + quad*8 + j]
__device__ __forceinline__ half8 ldfrag16(const float* __restrict__ base, int rstride,
                                          int n0, int k0, int c16, int quad) {
  const float* p = base + (size_t)(n0 + c16) * rstride + k0 + quad * 8;
  f32x4 a = *(const f32x4*)p;
  f32x4 b = *(const f32x4*)(p + 4);
  half8 h;
  h[0] = (hf)a.x; h[1] = (hf)a.y; h[2] = (hf)a.z; h[3] = (hf)a.w;
  h[4] = (hf)b.x; h[5] = (hf)b.y; h[6] = (hf)b.z; h[7] = (hf)b.w;
  return h;
}

// ---- single fused kernel: one 512-thread wg per (cls,bn); no cross-wg traffic ----
__global__ __launch_bounds__(512) __attribute__((amdgpu_waves_per_eu(2, 2)))
void witran_all(const float* __restrict__ x,
                const float* __restrict__ fc3_w, const float* __restrict__ fc3_b,
                const float* __restrict__ fc4_w, const float* __restrict__ fc4_b,
                const float* __restrict__ W_enc, const float* __restrict__ B_enc,
                const float* __restrict__ fc1_w, const float* __restrict__ fc1_b,
                const float* __restrict__ fc2_w, const float* __restrict__ fc2_b,
                hf* __restrict__ xWb, float* __restrict__ out) {
  const int cls = blockIdx.x & 1, bn = blockIdx.x >> 1;
  const int t = threadIdx.x, lane = t & 63, wv = t >> 6;
  const int c16 = lane & 15, quad = lane >> 4;
  const int d = wv * 16 + c16;  // this lane's hidden dim

  __shared__ __attribute__((aligned(16))) char smem[SM_TOTAL];
  hf* xA = (hf*)smem;              // phase 1 overlay
  hf* hbuf = (hf*)(smem + 8192);   // phase 1 overlay
  hf* wlds = (hf*)smem;            // phase 2 (filled after phase 1)
  hf* Abase = (hf*)(smem + SM_A);
  float* red = (float*)(smem + SM_RED);

  const float* Wc = W_enc + (size_t)cls * 768 * 384;
  hf* xg = xWb + ((size_t)(cls * 64 + bn)) * 192 * 768;

  // ================= phase 1: frontend MLP + xW precompute (own slice) ===========
  {
    half8 w3[2], w4[4];
#pragma unroll
    for (int ks = 0; ks < 2; ++ks) w3[ks] = ldfrag16(fc3_w, 64, wv * 16, ks * 32, c16, quad);
#pragma unroll
    for (int ks = 0; ks < 4; ++ks) w4[ks] = ldfrag16(fc4_w, 128, wv * 16, ks * 32, c16, quad);
    const float b3v = fc3_b[d], b4v = fc4_b[d];

    for (int chunk = 0; chunk < 3; ++chunk) {
      const int l0 = chunk * 64;
      {  // stage x (64 rows x 64 cols) -> fp16 swizzled
        int r = t >> 3, cb = (t & 7) * 8;
        const float* xp = x + (((size_t)bn * 192 + l0 + r) * 64 + cb);
        f32x4 a = *(const f32x4*)xp, b = *(const f32x4*)(xp + 4);
        half8 h;
        h[0] = (hf)a.x; h[1] = (hf)a.y; h[2] = (hf)a.z; h[3] = (hf)a.w;
        h[4] = (hf)b.x; h[5] = (hf)b.y; h[6] = (hf)b.z; h[7] = (hf)b.w;
        *(half8*)&xA[xidx(r, cb)] = h;
      }
      __syncthreads();

      // fc3: relu(x @ w3^T + b3) -> hbuf
      {
        f32x4 acc[4] = {{0, 0, 0, 0}, {0, 0, 0, 0}, {0, 0, 0, 0}, {0, 0, 0, 0}};
#pragma unroll
        for (int mt = 0; mt < 4; ++mt) {
          half8 a0 = *(const half8*)&xA[xidx(mt * 16 + c16, quad * 8)];
          half8 a1 = *(const half8*)&xA[xidx(mt * 16 + c16, 32 + quad * 8)];
          acc[mt] = __builtin_amdgcn_mfma_f32_16x16x32_f16(a0, w3[0], acc[mt], 0, 0, 0);
          acc[mt] = __builtin_amdgcn_mfma_f32_16x16x32_f16(a1, w3[1], acc[mt], 0, 0, 0);
        }
#pragma unroll
        for (int mt = 0; mt < 4; ++mt)
#pragma unroll
          for (int r = 0; r < 4; ++r)
            hbuf[hidx(mt * 16 + quad * 4 + r, d)] = (hf)fmaxf(acc[mt][r] + b3v, 0.f);
      }
      __syncthreads();

      // fc4: h1 @ w4^T + b4 -> hbuf (read, barrier, overwrite)
      {
        f32x4 acc[4] = {{0, 0, 0, 0}, {0, 0, 0, 0}, {0, 0, 0, 0}, {0, 0, 0, 0}};
#pragma unroll
        for (int mt = 0; mt < 4; ++mt)
#pragma unroll
          for (int ks = 0; ks < 4; ++ks) {
            half8 a = *(const half8*)&hbuf[hidx(mt * 16 + c16, ks * 32 + quad * 8)];
            acc[mt] = __builtin_amdgcn_mfma_f32_16x16x32_f16(a, w4[ks], acc[mt], 0, 0, 0);
          }
        __syncthreads();
#pragma unroll
        for (int mt = 0; mt < 4; ++mt)
#pragma unroll
          for (int r = 0; r < 4; ++r)
            hbuf[hidx(mt * 16 + quad * 4 + r, d)] = (hf)(acc[mt][r] + b4v);
      }
      __syncthreads();

      // xW: hg @ Wx^T (+ masked bias) -> xg[l][d*6+gate]
      {
        half8 af[4][4];
#pragma unroll
        for (int mt = 0; mt < 4; ++mt)
#pragma unroll
          for (int ks = 0; ks < 4; ++ks)
            af[mt][ks] = *(const half8*)&hbuf[hidx(mt * 16 + c16, ks * 32 + quad * 8)];
        for (int gp = 0; gp < 3; ++gp) {  // gate pair (2gp, 2gp+1)
          half8 wfa[4], wfb[4];
#pragma unroll
          for (int ks = 0; ks < 4; ++ks) {
            wfa[ks] = ldfrag16(Wc, 384, (2 * gp) * 128 + wv * 16, 256 + ks * 32, c16, quad);
            wfb[ks] = ldfrag16(Wc, 384, (2 * gp + 1) * 128 + wv * 16, 256 + ks * 32, c16, quad);
          }
          float bva = B_enc[cls * 768 + (2 * gp) * 128 + d];
          float bvb = B_enc[cls * 768 + (2 * gp + 1) * 128 + d];
#pragma unroll
          for (int mt = 0; mt < 4; ++mt) {
            f32x4 aA = {0, 0, 0, 0}, aB = {0, 0, 0, 0};
#pragma unroll
            for (int ks = 0; ks < 4; ++ks) {
              aA = __builtin_amdgcn_mfma_f32_16x16x32_f16(af[mt][ks], wfa[ks], aA, 0, 0, 0);
              aB = __builtin_amdgcn_mfma_f32_16x16x32_f16(af[mt][ks], wfb[ks], aB, 0, 0, 0);
            }
#pragma unroll
            for (int r = 0; r < 4; ++r) {
              int l = l0 + mt * 16 + quad * 4 + r;
              float act = ((l / 12) + (l % 12)) < 12 ? 1.f : 0.f;  // bias mask: r_cell+c_cell<12
              half2v pk = {(hf)(aA[r] + act * bva), (hf)(aB[r] + act * bvb)};
              *(half2v*)&xg[(size_t)l * 768 + d * 6 + 2 * gp] = pk;
            }
          }
        }
      }
      __syncthreads();  // all hbuf/xA reads done before next chunk overwrites
    }
  }

  // ===== phase 1.5: recurrent weights -> 32 reg frags (g=0..3) + 16 LDS frags (g=4,5)
  half8 w_reg[4][8];
#pragma unroll
  for (int g = 0; g < 4; ++g)
#pragma unroll
    for (int ks = 0; ks < 8; ++ks)
      w_reg[g][ks] = ldfrag16(Wc, 384, g * 128 + wv * 16, ks * 32, c16, quad);
#pragma unroll
  for (int g = 0; g < 2; ++g)
#pragma unroll
    for (int ks = 0; ks < 8; ++ks) {
      half8 h = ldfrag16(Wc, 384, (4 + g) * 128 + wv * 16, ks * 32, c16, quad);
      *(half8*)&wlds[wv * 8192 + (g * 8 + ks) * 512 + lane * 8] = h;
    }
  for (int i = t; i < 4096; i += 512) ((int*)Abase)[i] = 0;  // zero both A buffers
  __threadfence();  // drain xg stores to L2 before phase-2 reads (same-wg, cross-wave)
  __syncthreads();

  // ================= phase 2: 27-step recurrence, 1 barrier/step =================
  for (int s = 0; s < Steps; ++s) {
    const hf* Ac = Abase + (s & 1) * 4096;
    hf* An = Abase + ((s + 1) & 1) * 4096;

    // this step's x-gate inputs (own-XCD L2; latency covered by GEMM)
    int xv[4][3];
#pragma unroll
    for (int r = 0; r < 4; ++r) {
      int c = quad * 4 + r, rr = s - c;
      if (quad < 3 && rr >= 0 && rr < 16) {
        const int* p = (const int*)(xg + (size_t)(rr * 12 + c) * 768 + d * 6);
        xv[r][0] = p[0]; xv[r][1] = p[1]; xv[r][2] = p[2];
      } else {
        xv[r][0] = 0; xv[r][1] = 0; xv[r][2] = 0;
      }
    }

    // GEMM: A(LDS, swizzled) x W(32 reg frags + 16 LDS frags), K=256
    f32x4 acc[6] = {{0, 0, 0, 0}, {0, 0, 0, 0}, {0, 0, 0, 0},
                    {0, 0, 0, 0}, {0, 0, 0, 0}, {0, 0, 0, 0}};
#pragma unroll
    for (int ks = 0; ks < 8; ++ks) {
      half8 a = *(const half8*)&Ac[aidx(c16, ks * 32 + quad * 8)];
      half8 l4 = *(const half8*)&wlds[wv * 8192 + ks * 512 + lane * 8];
      half8 l5 = *(const half8*)&wlds[wv * 8192 + (8 + ks) * 512 + lane * 8];
      acc[0] = __builtin_amdgcn_mfma_f32_16x16x32_f16(a, w_reg[0][ks], acc[0], 0, 0, 0);
      acc[1] = __builtin_amdgcn_mfma_f32_16x16x32_f16(a, w_reg[1][ks], acc[1], 0, 0, 0);
      acc[2] = __builtin_amdgcn_mfma_f32_16x16x32_f16(a, w_reg[2][ks], acc[2], 0, 0, 0);
      acc[3] = __builtin_amdgcn_mfma_f32_16x16x32_f16(a, w_reg[3][ks], acc[3], 0, 0, 0);
      acc[4] = __builtin_amdgcn_mfma_f32_16x16x32_f16(a, l4, acc[4], 0, 0, 0);
      acc[5] = __builtin_amdgcn_mfma_f32_16x16x32_f16(a, l5, acc[5], 0, 0, 0);
    }

    // in-register gated update; write h_row + rolled h_col into A_next
    if (quad < 3) {
#pragma unroll
      for (int r = 0; r < 4; ++r) {
        int c = quad * 4 + r;
        float hro = (float)Ac[aidx(c, d)];
        float hco = (float)Ac[aidx(c, 128 + d)];
        half2v x01 = __builtin_bit_cast(half2v, xv[r][0]);
        half2v x23 = __builtin_bit_cast(half2v, xv[r][1]);
        half2v x45 = __builtin_bit_cast(half2v, xv[r][2]);
        float ur = sigmoidf_(acc[0][r] + (float)x01[0]);
        float orr = sigmoidf_(acc[1][r] + (float)x01[1]);
        float uc = sigmoidf_(acc[2][r] + (float)x23[0]);
        float oc = sigmoidf_(acc[3][r] + (float)x23[1]);
        float ir = tanh_(acc[4][r] + (float)x45[0]);
        float ic = tanh_(acc[5][r] + (float)x45[1]);
        float hr = tanh_((1.f - ur) * hro + ur * ir) * orr;
        float hc = tanh_((1.f - uc) * hco + uc * ic) * oc;
        An[aidx(c, d)] = (hf)hr;
        int c2 = (c == 11) ? 0 : c + 1;  // roll: new h_col[c] feeds slice c+1
        An[aidx(c2, 128 + d)] = (hf)hc;
      }
    }
    __syncthreads();  // A_next complete (no WAR: An != Ac)
  }

  // ---- epilogue: h_row[11] at A[11][0:128); rolled h_col[11] at A[0][128:256) ----
  {
    const hf* Af = Abase + (Steps & 1) * 4096;
    if (t < 128) {
      float hr = (float)Af[aidx(11, t)];
      float hc = (float)Af[aidx(0, 128 + t)];
      red[t] = 0.5f * (hc * fc1_w[cls * 128 + t] + hr * fc2_w[cls * 128 + t]);
    }
    __syncthreads();
    if (t == 0) {
      float sum = 0.f;
      for (int i = 0; i < 128; ++i) sum += red[i];
      out[bn * 2 + cls] = sum + 0.5f * (fc1_b[cls] + fc2_b[cls]);
    }
  }
}

extern "C" void kernel_launch(void* const* d_in, const int* in_sizes, int n_in,
                              void* d_out, int out_size, void* d_ws, size_t ws_size,
                              hipStream_t stream) {
  const float* x = (const float*)d_in[0];
  // d_in[1] = pad_mask: unused by the reference
  const float* fc3_w = (const float*)d_in[2];
  const float* fc3_b = (const float*)d_in[3];
  const float* fc4_w = (const float*)d_in[4];
  const float* fc4_b = (const float*)d_in[5];
  const float* W_enc = (const float*)d_in[6];
  const float* B_enc = (const float*)d_in[7];
  const float* fc1_w = (const float*)d_in[8];
  const float* fc1_b = (const float*)d_in[9];
  const float* fc2_w = (const float*)d_in[10];
  const float* fc2_b = (const float*)d_in[11];
  float* out = (float*)d_out;

  hf* xWb = (hf*)d_ws;  // 2 x 64 x 192 x 768 x 2 B = 37,748,736 B

  witran_all<<<dim3(128), dim3(512), 0, stream>>>(x, fc3_w, fc3_b, fc4_w, fc4_b,
                                                  W_enc, B_enc, fc1_w, fc1_b, fc2_w, fc2_b,
                                                  xWb, out);
}

// Round 9
// 194.964 us; speedup vs baseline: 1.3556x; 1.3556x over previous
//
#include <hip/hip_runtime.h>

typedef _Float16 hf;
typedef _Float16 half2v __attribute__((ext_vector_type(2)));
typedef _Float16 half8 __attribute__((ext_vector_type(8)));
typedef float f32x4 __attribute__((ext_vector_type(4)));
typedef int int4v __attribute__((ext_vector_type(4)));

constexpr int Steps = 27;

// ws half-index layout:
//   wrec : [0, 393216)          (((cls*8+wv)*6+gate)*8+ks)*512 + lane*8 + j   K=[0,256)
//   wx   : [393216, 589824)     (((cls*6+gate)*8+wv)*4+ks)*512 + lane*8 + j   K=[256,384)
//   fc3  : [589824, 598016)     (wv*2+ks)*512 + lane*8 + j
//   fc4  : [598016, 614400)     (wv*4+ks)*512 + lane*8 + j
//   xWb  : [614400, +18874368)  [cls][bn][cell][d*6+gate] fp16
constexpr int OFF_WX = 393216;
constexpr int OFF_F3 = 589824;
constexpr int OFF_F4 = 598016;
constexpr int OFF_XW = 614400;

__device__ __forceinline__ int aidx(int r, int k) {  // halfs, K=256 (witran A)
  int blk = k >> 3;
  return r * 256 + (((blk ^ (r & 7)) & 31) << 3) + (k & 7);
}
__device__ __forceinline__ int hidx(int r, int k) {  // halfs, K=128 (prelude h buffers)
  int blk = k >> 3;
  return r * 128 + (((blk ^ (r & 15)) & 15) << 3) + (k & 7);
}
__device__ __forceinline__ int xidx(int r, int k) {  // halfs, K=64 (prelude x)
  int blk = k >> 3;
  return r * 64 + (((blk ^ (r & 7)) & 7) << 3) + (k & 7);
}
__device__ __forceinline__ float sigmoidf_(float x) { return 1.0f / (1.0f + __expf(-x)); }
__device__ __forceinline__ float tanh_(float x) { return 1.0f - 2.0f / (__expf(2.0f * x) + 1.0f); }

// ---- kernel 1: all weights -> fragment-ordered fp16 (coalesced writes) ----
__global__ __launch_bounds__(512) void prep(const float* __restrict__ fc3_w,
                                            const float* __restrict__ fc4_w,
                                            const float* __restrict__ W_enc,
                                            hf* __restrict__ wsh) {
  int idx = blockIdx.x * 512 + threadIdx.x;
  if (idx >= OFF_XW) return;
  float v;
  if (idx < OFF_WX) {  // recurrent W, K in [0,256), gate-permuted per wave
    int j = idx & 7, lane = (idx >> 3) & 63, rest = idx >> 9;
    int ks = rest & 7; rest >>= 3;
    int gate = rest % 6; rest /= 6;
    int wv = rest & 7, cls = rest >> 3;
    int n = gate * 128 + wv * 16 + (lane & 15);
    int k = ks * 32 + ((lane >> 4) << 3) + j;
    v = W_enc[(cls * 768 + n) * 384 + k];
  } else if (idx < OFF_F3) {  // x-part Wx, K in [256,384)
    int f = idx - OFF_WX;
    int j = f & 7, lane = (f >> 3) & 63, rest = f >> 9;
    int ks = rest & 3; rest >>= 2;
    int wv = rest & 7; rest >>= 3;
    int gate = rest % 6, cls = rest / 6;
    int n = gate * 128 + wv * 16 + (lane & 15);
    int k = 256 + ks * 32 + ((lane >> 4) << 3) + j;
    v = W_enc[(cls * 768 + n) * 384 + k];
  } else if (idx < OFF_F4) {  // fc3
    int f = idx - OFF_F3;
    int j = f & 7, lane = (f >> 3) & 63, rest = f >> 9;
    int ks = rest & 1, wv = rest >> 1;
    int n = wv * 16 + (lane & 15), k = ks * 32 + ((lane >> 4) << 3) + j;
    v = fc3_w[n * 64 + k];
  } else {  // fc4
    int f = idx - OFF_F4;
    int j = f & 7, lane = (f >> 3) & 63, rest = f >> 9;
    int ks = rest & 3, wv = rest >> 2;
    int n = wv * 16 + (lane & 15), k = ks * 32 + ((lane >> 4) << 3) + j;
    v = fc4_w[n * 128 + k];
  }
  wsh[idx] = (hf)v;
}

// ---- kernel 2: frontend MLP + xW precompute; xWb written coalesced via LDS staging ----
__global__ __launch_bounds__(512) void prelude(
    const float* __restrict__ x, const float* __restrict__ fc3_b, const float* __restrict__ fc4_b,
    const float* __restrict__ B_enc, const hf* __restrict__ wsh, hf* __restrict__ xWb) {
  const int t = threadIdx.x, lane = t & 63, wv = t >> 6;
  const int c16 = lane & 15, quad = lane >> 4;
  const int row0 = blockIdx.x * 64, bn = row0 / 192, l0 = row0 % 192;

  __shared__ __attribute__((aligned(16))) hf xA[64 * 64];
  __shared__ __attribute__((aligned(16))) hf hbuf[64 * 128];
  __shared__ __attribute__((aligned(16))) hf xout[64 * 768];
  __shared__ float actf[64];

  {  // stage x -> fp16 swizzled LDS
    int r = t >> 3, cb = (t & 7) * 8;
    const float* xp = x + (size_t)(row0 + r) * 64 + cb;
    f32x4 a = *(const f32x4*)xp, b = *(const f32x4*)(xp + 4);
    half8 h;
    h[0] = (hf)a.x; h[1] = (hf)a.y; h[2] = (hf)a.z; h[3] = (hf)a.w;
    h[4] = (hf)b.x; h[5] = (hf)b.y; h[6] = (hf)b.z; h[7] = (hf)b.w;
    *(half8*)&xA[xidx(r, cb)] = h;
  }
  if (t < 64) {
    int l = l0 + t;
    actf[t] = ((l / 12) + (l % 12)) < 12 ? 1.f : 0.f;
  }
  __syncthreads();

  // ---- fc3: relu(x @ w3^T + b3) -> hbuf ----
  {
    float b3v = fc3_b[wv * 16 + c16];
    half8 w0 = *(const half8*)(wsh + OFF_F3 + (wv * 2 + 0) * 512 + lane * 8);
    half8 w1 = *(const half8*)(wsh + OFF_F3 + (wv * 2 + 1) * 512 + lane * 8);
    f32x4 acc[4] = {{0, 0, 0, 0}, {0, 0, 0, 0}, {0, 0, 0, 0}, {0, 0, 0, 0}};
#pragma unroll
    for (int mt = 0; mt < 4; ++mt) {
      half8 a0 = *(const half8*)&xA[xidx(mt * 16 + c16, quad * 8)];
      half8 a1 = *(const half8*)&xA[xidx(mt * 16 + c16, 32 + quad * 8)];
      acc[mt] = __builtin_amdgcn_mfma_f32_16x16x32_f16(a0, w0, acc[mt], 0, 0, 0);
      acc[mt] = __builtin_amdgcn_mfma_f32_16x16x32_f16(a1, w1, acc[mt], 0, 0, 0);
    }
#pragma unroll
    for (int mt = 0; mt < 4; ++mt)
#pragma unroll
      for (int r = 0; r < 4; ++r)
        hbuf[hidx(mt * 16 + quad * 4 + r, wv * 16 + c16)] = (hf)fmaxf(acc[mt][r] + b3v, 0.f);
  }
  __syncthreads();

  // ---- fc4: h1 @ w4^T + b4 -> hbuf (after barrier) ----
  {
    float b4v = fc4_b[wv * 16 + c16];
    half8 w4[4];
#pragma unroll
    for (int ks = 0; ks < 4; ++ks)
      w4[ks] = *(const half8*)(wsh + OFF_F4 + (wv * 4 + ks) * 512 + lane * 8);
    f32x4 acc[4] = {{0, 0, 0, 0}, {0, 0, 0, 0}, {0, 0, 0, 0}, {0, 0, 0, 0}};
#pragma unroll
    for (int mt = 0; mt < 4; ++mt)
#pragma unroll
      for (int ks = 0; ks < 4; ++ks) {
        half8 a = *(const half8*)&hbuf[hidx(mt * 16 + c16, ks * 32 + quad * 8)];
        acc[mt] = __builtin_amdgcn_mfma_f32_16x16x32_f16(a, w4[ks], acc[mt], 0, 0, 0);
      }
    __syncthreads();  // all h1 reads done before overwrite
#pragma unroll
    for (int mt = 0; mt < 4; ++mt)
#pragma unroll
      for (int r = 0; r < 4; ++r)
        hbuf[hidx(mt * 16 + quad * 4 + r, wv * 16 + c16)] = (hf)(acc[mt][r] + b4v);
  }
  __syncthreads();

  // ---- xW: hg @ Wx^T (+ masked bias); wave wv owns d in [wv*16,+16), all 6 gates ----
  half8 af[4][4];
#pragma unroll
  for (int mt = 0; mt < 4; ++mt)
#pragma unroll
    for (int ks = 0; ks < 4; ++ks)
      af[mt][ks] = *(const half8*)&hbuf[hidx(mt * 16 + c16, ks * 32 + quad * 8)];

  for (int cls = 0; cls < 2; ++cls) {
    for (int gp = 0; gp < 3; ++gp) {  // gate pair (2gp, 2gp+1), packed dword staging
      half8 wfa[4], wfb[4];
#pragma unroll
      for (int ks = 0; ks < 4; ++ks) {
        wfa[ks] = *(const half8*)(wsh + OFF_WX + ((((cls * 6 + 2 * gp) * 8 + wv) * 4) + ks) * 512 + lane * 8);
        wfb[ks] = *(const half8*)(wsh + OFF_WX + ((((cls * 6 + 2 * gp + 1) * 8 + wv) * 4) + ks) * 512 + lane * 8);
      }
      float bva = B_enc[cls * 768 + (2 * gp) * 128 + wv * 16 + c16];
      float bvb = B_enc[cls * 768 + (2 * gp + 1) * 128 + wv * 16 + c16];
#pragma unroll
      for (int mt = 0; mt < 4; ++mt) {
        f32x4 aA = {0, 0, 0, 0}, aB = {0, 0, 0, 0};
#pragma unroll
        for (int ks = 0; ks < 4; ++ks) {
          aA = __builtin_amdgcn_mfma_f32_16x16x32_f16(af[mt][ks], wfa[ks], aA, 0, 0, 0);
          aB = __builtin_amdgcn_mfma_f32_16x16x32_f16(af[mt][ks], wfb[ks], aB, 0, 0, 0);
        }
#pragma unroll
        for (int r = 0; r < 4; ++r) {
          int row = mt * 16 + quad * 4 + r;
          half2v pk = {(hf)(aA[r] + actf[row] * bva), (hf)(aB[r] + actf[row] * bvb)};
          *(half2v*)&xout[row * 768 + (wv * 16 + c16) * 6 + 2 * gp] = pk;
        }
      }
    }
    __syncthreads();  // xout complete for this class
    {  // coalesced write: 64 rows x 768 halfs = 24576 dwords
      const int* src = (const int*)xout;
      int* dst = (int*)(xWb + (((size_t)cls * 64 + bn) * 192 + l0) * 768);
#pragma unroll
      for (int i = 0; i < 12; ++i) {
        int base = (t + i * 512) * 4;
        *(int4v*)&dst[base] = *(const int4v*)&src[base];
      }
    }
    __syncthreads();  // writes done before xout reuse
  }
}

// ---- kernel 3: recurrence; 4 sigmoid-gate weight sets in regs (AGPR), 2 tanh-gate
//      sets in LDS; in-register update; A ping-pong; 1 barrier/step ----
__global__ __launch_bounds__(512) __attribute__((amdgpu_waves_per_eu(2, 2))) void witran(
    const hf* __restrict__ wsh, const float* __restrict__ fc1_w, const float* __restrict__ fc1_b,
    const float* __restrict__ fc2_w, const float* __restrict__ fc2_b,
    const hf* __restrict__ xWb, float* __restrict__ out) {
  const int cls = blockIdx.x & 1, bn = blockIdx.x >> 1;
  const int t = threadIdx.x, lane = t & 63, wv = t >> 6;
  const int c16 = lane & 15, quad = lane >> 4;
  const int d = wv * 16 + c16;  // this lane's dim

  __shared__ __attribute__((aligned(16))) hf wlds[8 * 8192];  // per-wave 16 KB: g=4,5 x ks=0..7
  __shared__ __attribute__((aligned(16))) hf A[2][16 * 256];
  __shared__ float red[128];

  for (int i = t; i < 4096; i += 512) ((int*)A)[i] = 0;

  // gates 0..3 (sigmoid) -> registers (AGPR half of the unified file)
  half8 w_reg[4][8];
#pragma unroll
  for (int g = 0; g < 4; ++g)
#pragma unroll
    for (int ks = 0; ks < 8; ++ks)
      w_reg[g][ks] = *(const half8*)(wsh + ((((cls * 8 + wv) * 6 + g) * 8) + ks) * 512 + lane * 8);

  // gates 4,5 (tanh) -> per-wave LDS (coalesced copy from fragment table)
#pragma unroll
  for (int f = 0; f < 16; ++f) {
    half8 h = *(const half8*)(wsh + ((((cls * 8 + wv) * 6 + 4 + (f >> 3)) * 8) + (f & 7)) * 512 + lane * 8);
    *(half8*)&wlds[wv * 8192 + f * 512 + lane * 8] = h;
  }

  const hf* xg = xWb + ((size_t)cls * 64 + bn) * 192 * 768;

  // xv for step 0: per slice r (c = quad*4+r), 6 gate inputs = 3 dwords
  int xv[4][3], xvn[4][3];
#pragma unroll
  for (int r = 0; r < 4; ++r) {
    int c = quad * 4 + r;
    if (quad < 3 && c == 0) {  // rr = 0 - c valid only for c == 0
      const int* p = (const int*)(xg + (size_t)c * 768 + d * 6);
      xv[r][0] = p[0]; xv[r][1] = p[1]; xv[r][2] = p[2];
    } else {
      xv[r][0] = 0; xv[r][1] = 0; xv[r][2] = 0;
    }
  }
  __syncthreads();  // A zero-init + wlds visible

  for (int s = 0; s < Steps; ++s) {
    const hf* Ac = A[s & 1];
    hf* An = A[(s + 1) & 1];

    // ---- prefetch next step's x-gates (full-step slack) ----
#pragma unroll
    for (int r = 0; r < 4; ++r) {
      int c = quad * 4 + r, rr = (s + 1) - c;
      if (quad < 3 && rr >= 0 && rr < 16) {
        const int* p = (const int*)(xg + (size_t)(rr * 12 + c) * 768 + d * 6);
        xvn[r][0] = p[0]; xvn[r][1] = p[1]; xvn[r][2] = p[2];
      } else {
        xvn[r][0] = 0; xvn[r][1] = 0; xvn[r][2] = 0;
      }
    }

    // ---- GEMM: A(LDS, swizzled) x W(4 reg + 2 LDS gate sets), K=256 ----
    f32x4 acc[6] = {{0, 0, 0, 0}, {0, 0, 0, 0}, {0, 0, 0, 0},
                    {0, 0, 0, 0}, {0, 0, 0, 0}, {0, 0, 0, 0}};
#pragma unroll
    for (int ks = 0; ks < 8; ++ks) {
      half8 a = *(const half8*)&Ac[aidx(c16, ks * 32 + quad * 8)];
      half8 l4 = *(const half8*)&wlds[wv * 8192 + ks * 512 + lane * 8];
      half8 l5 = *(const half8*)&wlds[wv * 8192 + (8 + ks) * 512 + lane * 8];
      acc[0] = __builtin_amdgcn_mfma_f32_16x16x32_f16(a, w_reg[0][ks], acc[0], 0, 0, 0);
      acc[1] = __builtin_amdgcn_mfma_f32_16x16x32_f16(a, w_reg[1][ks], acc[1], 0, 0, 0);
      acc[2] = __builtin_amdgcn_mfma_f32_16x16x32_f16(a, w_reg[2][ks], acc[2], 0, 0, 0);
      acc[3] = __builtin_amdgcn_mfma_f32_16x16x32_f16(a, w_reg[3][ks], acc[3], 0, 0, 0);
      acc[4] = __builtin_amdgcn_mfma_f32_16x16x32_f16(a, l4, acc[4], 0, 0, 0);
      acc[5] = __builtin_amdgcn_mfma_f32_16x16x32_f16(a, l5, acc[5], 0, 0, 0);
    }

    // ---- in-register gated update; write h_row + rolled h_col into A_next ----
    if (quad < 3) {
#pragma unroll
      for (int r = 0; r < 4; ++r) {
        int c = quad * 4 + r;
        float hro = (float)Ac[aidx(c, d)];
        float hco = (float)Ac[aidx(c, 128 + d)];
        half2v x01 = __builtin_bit_cast(half2v, xv[r][0]);
        half2v x23 = __builtin_bit_cast(half2v, xv[r][1]);
        half2v x45 = __builtin_bit_cast(half2v, xv[r][2]);
        float ur = sigmoidf_(acc[0][r] + (float)x01[0]);
        float orr = sigmoidf_(acc[1][r] + (float)x01[1]);
        float uc = sigmoidf_(acc[2][r] + (float)x23[0]);
        float oc = sigmoidf_(acc[3][r] + (float)x23[1]);
        float ir = tanh_(acc[4][r] + (float)x45[0]);
        float ic = tanh_(acc[5][r] + (float)x45[1]);
        float hr = tanh_((1.f - ur) * hro + ur * ir) * orr;
        float hc = tanh_((1.f - uc) * hco + uc * ic) * oc;
        An[aidx(c, d)] = (hf)hr;
        int c2 = (c == 11) ? 0 : c + 1;  // roll: new h_col[c] feeds slice c+1
        An[aidx(c2, 128 + d)] = (hf)hc;
      }
    }
    __syncthreads();  // A_next complete (no WAR: An != Ac)

#pragma unroll
    for (int r = 0; r < 4; ++r) {
      xv[r][0] = xvn[r][0]; xv[r][1] = xvn[r][1]; xv[r][2] = xvn[r][2];
    }
  }

  // ---- epilogue: final state in A[Steps&1] = A[1] ----
  if (t < 128) {
    float hr = (float)A[1][aidx(11, t)];
    float hc = (float)A[1][aidx(0, 128 + t)];
    red[t] = 0.5f * (hc * fc1_w[cls * 128 + t] + hr * fc2_w[cls * 128 + t]);
  }
  __syncthreads();
  if (t == 0) {
    float sum = 0.f;
    for (int i = 0; i < 128; ++i) sum += red[i];
    out[bn * 2 + cls] = sum + 0.5f * (fc1_b[cls] + fc2_b[cls]);
  }
}

extern "C" void kernel_launch(void* const* d_in, const int* in_sizes, int n_in,
                              void* d_out, int out_size, void* d_ws, size_t ws_size,
                              hipStream_t stream) {
  const float* x = (const float*)d_in[0];
  // d_in[1] = pad_mask: unused by the reference
  const float* fc3_w = (const float*)d_in[2];
  const float* fc3_b = (const float*)d_in[3];
  const float* fc4_w = (const float*)d_in[4];
  const float* fc4_b = (const float*)d_in[5];
  const float* W_enc = (const float*)d_in[6];
  const float* B_enc = (const float*)d_in[7];
  const float* fc1_w = (const float*)d_in[8];
  const float* fc1_b = (const float*)d_in[9];
  const float* fc2_w = (const float*)d_in[10];
  const float* fc2_b = (const float*)d_in[11];
  float* out = (float*)d_out;

  hf* wsh = (hf*)d_ws;        // frag tables 1,228,800 B
  hf* xWb = wsh + OFF_XW;     // 37,748,736 B ; total 38,977,536 B

  prep<<<dim3(1200), dim3(512), 0, stream>>>(fc3_w, fc4_w, W_enc, wsh);
  prelude<<<dim3(192), dim3(512), 0, stream>>>(x, fc3_b, fc4_b, B_enc, wsh, xWb);
  witran<<<dim3(128), dim3(512), 0, stream>>>(wsh, fc1_w, fc1_b, fc2_w, fc2_b, xWb, out);
}

// Round 10
// 194.929 us; speedup vs baseline: 1.3558x; 1.0002x over previous
//
#include <hip/hip_runtime.h>

typedef _Float16 hf;
typedef _Float16 half2v __attribute__((ext_vector_type(2)));
typedef _Float16 half8 __attribute__((ext_vector_type(8)));
typedef float f32x4 __attribute__((ext_vector_type(4)));
typedef int int4v __attribute__((ext_vector_type(4)));

constexpr int Steps = 27;

// ws half-index layout:
//   wrec : [0, 393216)         (((cls*16+wv)*3+j)*8+ks)*512 + lane*8 + jj
//          wave wv<8: row gates {u_r,o_r,i_r}; wv>=8: col gates {u_c,o_c,i_c}; d=(wv&7)*16+..
//   wx   : [393216, 589824)    (((cls*6+g)*8+wv)*4+ks)*512 + lane*8 + j   K=[256,384)
//   fc3  : [589824, 598016)
//   fc4  : [598016, 614400)
//   xWb  : [614400, +18874368)  [cls][bn][cell][d*6 + pos], pos: 0,1,2=u_r,o_r,i_r; 3,4,5=u_c,o_c,i_c
constexpr int OFF_WX = 393216;
constexpr int OFF_F3 = 589824;
constexpr int OFF_F4 = 598016;
constexpr int OFF_XW = 614400;
constexpr int GST = 7;  // g_lds per-(c,d) stride (floats): 7 -> conflict-free

__device__ __forceinline__ int aidx(int r, int k) {  // halfs, K=256 (witran A)
  int blk = k >> 3;
  return r * 256 + (((blk ^ (r & 7)) & 31) << 3) + (k & 7);
}
__device__ __forceinline__ int hidx(int r, int k) {  // halfs, K=128 (prelude h buffers)
  int blk = k >> 3;
  return r * 128 + (((blk ^ (r & 15)) & 15) << 3) + (k & 7);
}
__device__ __forceinline__ int xidx(int r, int k) {  // halfs, K=64 (prelude x)
  int blk = k >> 3;
  return r * 64 + (((blk ^ (r & 7)) & 7) << 3) + (k & 7);
}
__device__ __forceinline__ float sigmoidf_(float x) { return 1.0f / (1.0f + __expf(-x)); }
__device__ __forceinline__ float tanh_(float x) { return 1.0f - 2.0f / (__expf(2.0f * x) + 1.0f); }

// ---- kernel 1: all weights -> fragment-ordered fp16 ----
__global__ __launch_bounds__(512) void prep(const float* __restrict__ fc3_w,
                                            const float* __restrict__ fc4_w,
                                            const float* __restrict__ W_enc,
                                            hf* __restrict__ wsh) {
  int idx = blockIdx.x * 512 + threadIdx.x;
  if (idx >= OFF_XW) return;
  float v;
  if (idx < OFF_WX) {  // recurrent W, gate-triple per wave
    int jj = idx & 7, lane = (idx >> 3) & 63, rest = idx >> 9;
    int ks = rest & 7; rest >>= 3;
    int j = rest % 3; rest /= 3;
    int wv = rest & 15, cls = rest >> 4;
    int gate = (wv < 8) ? (j < 2 ? j : 4) : (j < 2 ? j + 2 : 5);  // {0,1,4} / {2,3,5}
    int n = gate * 128 + (wv & 7) * 16 + (lane & 15);
    int k = ks * 32 + ((lane >> 4) << 3) + jj;
    v = W_enc[(cls * 768 + n) * 384 + k];
  } else if (idx < OFF_F3) {  // x-part Wx
    int f = idx - OFF_WX;
    int j = f & 7, lane = (f >> 3) & 63, rest = f >> 9;
    int ks = rest & 3; rest >>= 2;
    int wv = rest & 7; rest >>= 3;
    int gate = rest % 6, cls = rest / 6;
    int n = gate * 128 + wv * 16 + (lane & 15);
    int k = 256 + ks * 32 + ((lane >> 4) << 3) + j;
    v = W_enc[(cls * 768 + n) * 384 + k];
  } else if (idx < OFF_F4) {  // fc3
    int f = idx - OFF_F3;
    int j = f & 7, lane = (f >> 3) & 63, rest = f >> 9;
    int ks = rest & 1, wv = rest >> 1;
    int n = wv * 16 + (lane & 15), k = ks * 32 + ((lane >> 4) << 3) + j;
    v = fc3_w[n * 64 + k];
  } else {  // fc4
    int f = idx - OFF_F4;
    int j = f & 7, lane = (f >> 3) & 63, rest = f >> 9;
    int ks = rest & 3, wv = rest >> 2;
    int n = wv * 16 + (lane & 15), k = ks * 32 + ((lane >> 4) << 3) + j;
    v = fc4_w[n * 128 + k];
  }
  wsh[idx] = (hf)v;
}

// ---- kernel 2: frontend MLP + xW precompute; xWb pos-ordered, coalesced store ----
__global__ __launch_bounds__(512) void prelude(
    const float* __restrict__ x, const float* __restrict__ fc3_b, const float* __restrict__ fc4_b,
    const float* __restrict__ B_enc, const hf* __restrict__ wsh, hf* __restrict__ xWb) {
  const int t = threadIdx.x, lane = t & 63, wv = t >> 6;
  const int c16 = lane & 15, quad = lane >> 4;
  const int row0 = blockIdx.x * 64, bn = row0 / 192, l0 = row0 % 192;
  const int d = wv * 16 + c16;

  __shared__ __attribute__((aligned(16))) hf xA[64 * 64];
  __shared__ __attribute__((aligned(16))) hf hbuf[64 * 128];
  __shared__ __attribute__((aligned(16))) hf xout[64 * 768];
  __shared__ float actf[64];

  {  // stage x -> fp16 swizzled LDS
    int r = t >> 3, cb = (t & 7) * 8;
    const float* xp = x + (size_t)(row0 + r) * 64 + cb;
    f32x4 a = *(const f32x4*)xp, b = *(const f32x4*)(xp + 4);
    half8 h;
    h[0] = (hf)a.x; h[1] = (hf)a.y; h[2] = (hf)a.z; h[3] = (hf)a.w;
    h[4] = (hf)b.x; h[5] = (hf)b.y; h[6] = (hf)b.z; h[7] = (hf)b.w;
    *(half8*)&xA[xidx(r, cb)] = h;
  }
  if (t < 64) {
    int l = l0 + t;
    actf[t] = ((l / 12) + (l % 12)) < 12 ? 1.f : 0.f;
  }
  __syncthreads();

  // fc3
  {
    float b3v = fc3_b[d];
    half8 w0 = *(const half8*)(wsh + OFF_F3 + (wv * 2 + 0) * 512 + lane * 8);
    half8 w1 = *(const half8*)(wsh + OFF_F3 + (wv * 2 + 1) * 512 + lane * 8);
    f32x4 acc[4] = {{0, 0, 0, 0}, {0, 0, 0, 0}, {0, 0, 0, 0}, {0, 0, 0, 0}};
#pragma unroll
    for (int mt = 0; mt < 4; ++mt) {
      half8 a0 = *(const half8*)&xA[xidx(mt * 16 + c16, quad * 8)];
      half8 a1 = *(const half8*)&xA[xidx(mt * 16 + c16, 32 + quad * 8)];
      acc[mt] = __builtin_amdgcn_mfma_f32_16x16x32_f16(a0, w0, acc[mt], 0, 0, 0);
      acc[mt] = __builtin_amdgcn_mfma_f32_16x16x32_f16(a1, w1, acc[mt], 0, 0, 0);
    }
#pragma unroll
    for (int mt = 0; mt < 4; ++mt)
#pragma unroll
      for (int r = 0; r < 4; ++r)
        hbuf[hidx(mt * 16 + quad * 4 + r, d)] = (hf)fmaxf(acc[mt][r] + b3v, 0.f);
  }
  __syncthreads();

  // fc4
  {
    float b4v = fc4_b[d];
    half8 w4[4];
#pragma unroll
    for (int ks = 0; ks < 4; ++ks)
      w4[ks] = *(const half8*)(wsh + OFF_F4 + (wv * 4 + ks) * 512 + lane * 8);
    f32x4 acc[4] = {{0, 0, 0, 0}, {0, 0, 0, 0}, {0, 0, 0, 0}, {0, 0, 0, 0}};
#pragma unroll
    for (int mt = 0; mt < 4; ++mt)
#pragma unroll
      for (int ks = 0; ks < 4; ++ks) {
        half8 a = *(const half8*)&hbuf[hidx(mt * 16 + c16, ks * 32 + quad * 8)];
        acc[mt] = __builtin_amdgcn_mfma_f32_16x16x32_f16(a, w4[ks], acc[mt], 0, 0, 0);
      }
    __syncthreads();
#pragma unroll
    for (int mt = 0; mt < 4; ++mt)
#pragma unroll
      for (int r = 0; r < 4; ++r)
        hbuf[hidx(mt * 16 + quad * 4 + r, d)] = (hf)(acc[mt][r] + b4v);
  }
  __syncthreads();

  // xW: per orig-gate g, store into pos {0,1,3,4,2,5}[g] of the 6-group
  half8 af[4][4];
#pragma unroll
  for (int mt = 0; mt < 4; ++mt)
#pragma unroll
    for (int ks = 0; ks < 4; ++ks)
      af[mt][ks] = *(const half8*)&hbuf[hidx(mt * 16 + c16, ks * 32 + quad * 8)];

  for (int cls = 0; cls < 2; ++cls) {
    for (int g = 0; g < 6; ++g) {
      int pos = (g < 2) ? g : (g < 4 ? g + 1 : (g == 4 ? 2 : 5));
      half8 wf[4];
#pragma unroll
      for (int ks = 0; ks < 4; ++ks)
        wf[ks] = *(const half8*)(wsh + OFF_WX + (((cls * 6 + g) * 8 + wv) * 4 + ks) * 512 + lane * 8);
      float bv = B_enc[cls * 768 + g * 128 + d];
#pragma unroll
      for (int mt = 0; mt < 4; ++mt) {
        f32x4 acc = {0.f, 0.f, 0.f, 0.f};
#pragma unroll
        for (int ks = 0; ks < 4; ++ks)
          acc = __builtin_amdgcn_mfma_f32_16x16x32_f16(af[mt][ks], wf[ks], acc, 0, 0, 0);
#pragma unroll
        for (int r = 0; r < 4; ++r) {
          int row = mt * 16 + quad * 4 + r;
          xout[row * 768 + d * 6 + pos] = (hf)(acc[r] + actf[row] * bv);
        }
      }
    }
    __syncthreads();  // xout complete for this class
    {
      const int* src = (const int*)xout;
      int* dst = (int*)(xWb + (((size_t)cls * 64 + bn) * 192 + l0) * 768);
#pragma unroll
      for (int i = 0; i < 12; ++i) {
        int base = (t + i * 512) * 4;
        *(int4v*)&dst[base] = *(const int4v*)&src[base];
      }
    }
    __syncthreads();
  }
}

// x-gate prefetch: unit u = t + i*1024; row units u<1536, col units >=1536
__device__ __forceinline__ void xpre(const hf* __restrict__ xg, int t, int sN,
                                     unsigned* pa, unsigned* pb) {
#pragma unroll
  for (int i = 0; i < 3; ++i) {
    int u = t + (i << 10);
    int colf = u >= 1536;
    int q = colf ? u - 1536 : u;
    int c = q >> 7, dd = q & 127;
    int rr = sN - c;
    unsigned a = 0, b = 0;
    if (rr >= 0 && rr < 16) {
      const hf* p = xg + (size_t)(rr * 12 + c) * 768 + dd * 6;
      if (colf) {  // pos 3 (ushort), pos 4,5 (dword)
        a = (unsigned)*(const unsigned short*)(p + 3);
        b = *(const unsigned*)(p + 4);
      } else {     // pos 0,1 (dword), pos 2 (ushort)
        a = *(const unsigned*)p;
        b = (unsigned)*(const unsigned short*)(p + 2);
      }
    }
    pa[i] = a;
    pb[i] = b;
  }
}
__device__ __forceinline__ float lo16f(unsigned v) {
  return (float)__builtin_bit_cast(half2v, v)[0];
}
__device__ __forceinline__ float hi16f(unsigned v) {
  return (float)__builtin_bit_cast(half2v, v)[1];
}

// ---- kernel 3: recurrence. 1024 threads; 16 waves = 4/SIMD; gate-split GEMM ----
__global__ __launch_bounds__(1024) __attribute__((amdgpu_waves_per_eu(4, 4))) void witran(
    const hf* __restrict__ wsh, const float* __restrict__ fc1_w, const float* __restrict__ fc1_b,
    const float* __restrict__ fc2_w, const float* __restrict__ fc2_b,
    const hf* __restrict__ xWb, float* __restrict__ out) {
  const int cls = blockIdx.x & 1, bn = blockIdx.x >> 1;
  const int t = threadIdx.x, lane = t & 63, wv = t >> 6;  // wv 0..15
  const int c16 = lane & 15, quad = lane >> 4;
  const int d = (wv & 7) * 16 + c16;
  const int goff = (wv < 8) ? 0 : 3;

  __shared__ __attribute__((aligned(16))) hf wlds[16 * 3072];  // 6 frags/wave (j=2, ks 2..7)
  __shared__ __attribute__((aligned(16))) hf A[2][4096];
  __shared__ float g_lds[12 * 128 * GST];
  __shared__ float red[128];

  for (int i = t; i < 4096; i += 1024) ((int*)A)[i] = 0;

  // weights: j=0,1 all ks in regs; j=2 ks 0,1 regs + ks 2..7 LDS
  half8 wr[2][8], wr2[2];
  {
    const hf* wb = wsh + (((size_t)(cls * 16 + wv) * 3) * 8) * 512 + lane * 8;
#pragma unroll
    for (int ks = 0; ks < 8; ++ks) {
      wr[0][ks] = *(const half8*)(wb + ks * 512);
      wr[1][ks] = *(const half8*)(wb + (8 + ks) * 512);
    }
    wr2[0] = *(const half8*)(wb + 16 * 512);
    wr2[1] = *(const half8*)(wb + 17 * 512);
#pragma unroll
    for (int f = 0; f < 6; ++f)
      *(half8*)&wlds[wv * 3072 + f * 512 + lane * 8] = *(const half8*)(wb + (18 + f) * 512);
  }

  const hf* xg = xWb + ((size_t)cls * 64 + bn) * 192 * 768;

  unsigned pa[3], pb[3], na[3], nb[3];
  xpre(xg, t, 0, pa, pb);
  __syncthreads();  // A zero + wlds visible

  for (int s = 0; s < Steps; ++s) {
    const hf* Ac = A[s & 1];
    hf* An = A[(s + 1) & 1];

    // ---- GEMM: own gate-triple, full K=256 ----
    f32x4 a0 = {0, 0, 0, 0}, a1 = a0, a2 = a0;
#pragma unroll
    for (int ks = 0; ks < 8; ++ks) {
      half8 av = *(const half8*)&Ac[aidx(c16, ks * 32 + quad * 8)];
      a0 = __builtin_amdgcn_mfma_f32_16x16x32_f16(av, wr[0][ks], a0, 0, 0, 0);
      a1 = __builtin_amdgcn_mfma_f32_16x16x32_f16(av, wr[1][ks], a1, 0, 0, 0);
      half8 w2 = (ks < 2) ? wr2[ks]
                          : *(const half8*)&wlds[wv * 3072 + (ks - 2) * 512 + lane * 8];
      a2 = __builtin_amdgcn_mfma_f32_16x16x32_f16(av, w2, a2, 0, 0, 0);
    }
    // spill gate-triple to g_lds (rows 0..11 only)
    if (quad < 3) {
#pragma unroll
      for (int r = 0; r < 4; ++r) {
        float* gp = &g_lds[((quad * 4 + r) * 128 + d) * GST + goff];
        gp[0] = a0[r];
        gp[1] = a1[r];
        gp[2] = a2[r];
      }
    }
    // prefetch next step's x-gates (latency covered by barrier+update)
    xpre(xg, t, s + 1, na, nb);
    __syncthreads();  // #1: g_lds complete

    // ---- update: 3 h-units per lane; skip inactive slices (wave-uniform) ----
#pragma unroll
    for (int i = 0; i < 3; ++i) {
      int u = t + (i << 10);
      int colf = u >= 1536;
      int q = colf ? u - 1536 : u;
      int c = q >> 7, dd = q & 127;
      if (c <= s) {
        const float* gp = &g_lds[(c * 128 + dd) * GST + (colf ? 3 : 0)];
        float xu, xo, xi;
        if (colf) {
          xu = lo16f(pa[i]); xo = lo16f(pb[i]); xi = hi16f(pb[i]);
        } else {
          xu = lo16f(pa[i]); xo = hi16f(pa[i]); xi = lo16f(pb[i]);
        }
        float gu = gp[0] + xu, go = gp[1] + xo, gi = gp[2] + xi;
        float hold = (float)Ac[aidx(c, colf ? 128 + dd : dd)];
        float uu = sigmoidf_(gu), oo = sigmoidf_(go), ii = tanh_(gi);
        float h = tanh_((1.f - uu) * hold + uu * ii) * oo;
        if (colf) {
          int c2 = (c == 11) ? 0 : c + 1;  // roll: new h_col[c] feeds slice c+1
          An[aidx(c2, 128 + dd)] = (hf)h;
        } else {
          An[aidx(c, dd)] = (hf)h;
        }
      }
    }
    __syncthreads();  // #2: A_next complete

#pragma unroll
    for (int i = 0; i < 3; ++i) { pa[i] = na[i]; pb[i] = nb[i]; }
  }

  // ---- epilogue: final state in A[Steps&1] = A[1] ----
  if (t < 128) {
    float hr = (float)A[1][aidx(11, t)];
    float hc = (float)A[1][aidx(0, 128 + t)];
    red[t] = 0.5f * (hc * fc1_w[cls * 128 + t] + hr * fc2_w[cls * 128 + t]);
  }
  __syncthreads();
  if (t == 0) {
    float sum = 0.f;
    for (int i = 0; i < 128; ++i) sum += red[i];
    out[bn * 2 + cls] = sum + 0.5f * (fc1_b[cls] + fc2_b[cls]);
  }
}

extern "C" void kernel_launch(void* const* d_in, const int* in_sizes, int n_in,
                              void* d_out, int out_size, void* d_ws, size_t ws_size,
                              hipStream_t stream) {
  const float* x = (const float*)d_in[0];
  // d_in[1] = pad_mask: unused by the reference
  const float* fc3_w = (const float*)d_in[2];
  const float* fc3_b = (const float*)d_in[3];
  const float* fc4_w = (const float*)d_in[4];
  const float* fc4_b = (const float*)d_in[5];
  const float* W_enc = (const float*)d_in[6];
  const float* B_enc = (const float*)d_in[7];
  const float* fc1_w = (const float*)d_in[8];
  const float* fc1_b = (const float*)d_in[9];
  const float* fc2_w = (const float*)d_in[10];
  const float* fc2_b = (const float*)d_in[11];
  float* out = (float*)d_out;

  hf* wsh = (hf*)d_ws;        // frag tables 1,228,800 B
  hf* xWb = wsh + OFF_XW;     // 37,748,736 B ; total 38,977,536 B (same as R9)

  prep<<<dim3(1200), dim3(512), 0, stream>>>(fc3_w, fc4_w, W_enc, wsh);
  prelude<<<dim3(192), dim3(512), 0, stream>>>(x, fc3_b, fc4_b, B_enc, wsh, xWb);
  witran<<<dim3(128), dim3(1024), 0, stream>>>(wsh, fc1_w, fc1_b, fc2_w, fc2_b, xWb, out);
}

// Round 11
// 189.109 us; speedup vs baseline: 1.3976x; 1.0308x over previous
//
#include <hip/hip_runtime.h>

typedef _Float16 hf;
typedef _Float16 half2v __attribute__((ext_vector_type(2)));
typedef _Float16 half8 __attribute__((ext_vector_type(8)));
typedef float f32x4 __attribute__((ext_vector_type(4)));
typedef int int4v __attribute__((ext_vector_type(4)));

constexpr int Steps = 27;

// ws half-index layout:
//   wrec : [0, 393216)         (((cls*16+wv)*3+j)*8+ks)*512 + lane*8 + jj
//          wave wv<8: row gates {u_r,o_r,i_r}; wv>=8: col gates {u_c,o_c,i_c}; d=(wv&7)*16+..
//   wx   : [393216, 589824)    (((cls*6+g)*8+wv)*4+ks)*512 + lane*8 + j   K=[256,384)
//   fc3  : [589824, 598016)
//   fc4  : [598016, 614400)
//   xWb  : [614400, +18874368)  [cls][bn][cell][d*6 + pos], pos: 0,1,2=u_r,o_r,i_r; 3,4,5=u_c,o_c,i_c
constexpr int OFF_WX = 393216;
constexpr int OFF_F3 = 589824;
constexpr int OFF_F4 = 598016;
constexpr int OFF_XW = 614400;
constexpr int CST = 136;  // g16 per-c stride (halfs): 136 -> quad rows land on shifted banks

__device__ __forceinline__ int aidx(int r, int k) {  // halfs, K=256 (witran A)
  int blk = k >> 3;
  return r * 256 + (((blk ^ (r & 7)) & 31) << 3) + (k & 7);
}
__device__ __forceinline__ int hidx(int r, int k) {  // halfs, K=128 (prelude h buffers)
  int blk = k >> 3;
  return r * 128 + (((blk ^ (r & 15)) & 15) << 3) + (k & 7);
}
__device__ __forceinline__ int xidx(int r, int k) {  // halfs, K=64 (prelude x)
  int blk = k >> 3;
  return r * 64 + (((blk ^ (r & 7)) & 7) << 3) + (k & 7);
}
__device__ __forceinline__ float sigmoidf_(float x) { return 1.0f / (1.0f + __expf(-x)); }
__device__ __forceinline__ float tanh_(float x) { return 1.0f - 2.0f / (__expf(2.0f * x) + 1.0f); }

// ---- kernel 1: all weights -> fragment-ordered fp16 ----
__global__ __launch_bounds__(512) void prep(const float* __restrict__ fc3_w,
                                            const float* __restrict__ fc4_w,
                                            const float* __restrict__ W_enc,
                                            hf* __restrict__ wsh) {
  int idx = blockIdx.x * 512 + threadIdx.x;
  if (idx >= OFF_XW) return;
  float v;
  if (idx < OFF_WX) {  // recurrent W, gate-triple per wave
    int jj = idx & 7, lane = (idx >> 3) & 63, rest = idx >> 9;
    int ks = rest & 7; rest >>= 3;
    int j = rest % 3; rest /= 3;
    int wv = rest & 15, cls = rest >> 4;
    int gate = (wv < 8) ? (j < 2 ? j : 4) : (j < 2 ? j + 2 : 5);  // {0,1,4} / {2,3,5}
    int n = gate * 128 + (wv & 7) * 16 + (lane & 15);
    int k = ks * 32 + ((lane >> 4) << 3) + jj;
    v = W_enc[(cls * 768 + n) * 384 + k];
  } else if (idx < OFF_F3) {  // x-part Wx
    int f = idx - OFF_WX;
    int j = f & 7, lane = (f >> 3) & 63, rest = f >> 9;
    int ks = rest & 3; rest >>= 2;
    int wv = rest & 7; rest >>= 3;
    int gate = rest % 6, cls = rest / 6;
    int n = gate * 128 + wv * 16 + (lane & 15);
    int k = 256 + ks * 32 + ((lane >> 4) << 3) + j;
    v = W_enc[(cls * 768 + n) * 384 + k];
  } else if (idx < OFF_F4) {  // fc3
    int f = idx - OFF_F3;
    int j = f & 7, lane = (f >> 3) & 63, rest = f >> 9;
    int ks = rest & 1, wv = rest >> 1;
    int n = wv * 16 + (lane & 15), k = ks * 32 + ((lane >> 4) << 3) + j;
    v = fc3_w[n * 64 + k];
  } else {  // fc4
    int f = idx - OFF_F4;
    int j = f & 7, lane = (f >> 3) & 63, rest = f >> 9;
    int ks = rest & 3, wv = rest >> 2;
    int n = wv * 16 + (lane & 15), k = ks * 32 + ((lane >> 4) << 3) + j;
    v = fc4_w[n * 128 + k];
  }
  wsh[idx] = (hf)v;
}

// ---- kernel 2: frontend MLP + xW precompute; xWb pos-ordered, coalesced store ----
__global__ __launch_bounds__(512) void prelude(
    const float* __restrict__ x, const float* __restrict__ fc3_b, const float* __restrict__ fc4_b,
    const float* __restrict__ B_enc, const hf* __restrict__ wsh, hf* __restrict__ xWb) {
  const int t = threadIdx.x, lane = t & 63, wv = t >> 6;
  const int c16 = lane & 15, quad = lane >> 4;
  const int row0 = blockIdx.x * 64, bn = row0 / 192, l0 = row0 % 192;
  const int d = wv * 16 + c16;

  __shared__ __attribute__((aligned(16))) hf xA[64 * 64];
  __shared__ __attribute__((aligned(16))) hf hbuf[64 * 128];
  __shared__ __attribute__((aligned(16))) hf xout[64 * 768];
  __shared__ float actf[64];

  {  // stage x -> fp16 swizzled LDS
    int r = t >> 3, cb = (t & 7) * 8;
    const float* xp = x + (size_t)(row0 + r) * 64 + cb;
    f32x4 a = *(const f32x4*)xp, b = *(const f32x4*)(xp + 4);
    half8 h;
    h[0] = (hf)a.x; h[1] = (hf)a.y; h[2] = (hf)a.z; h[3] = (hf)a.w;
    h[4] = (hf)b.x; h[5] = (hf)b.y; h[6] = (hf)b.z; h[7] = (hf)b.w;
    *(half8*)&xA[xidx(r, cb)] = h;
  }
  if (t < 64) {
    int l = l0 + t;
    actf[t] = ((l / 12) + (l % 12)) < 12 ? 1.f : 0.f;
  }
  __syncthreads();

  // fc3
  {
    float b3v = fc3_b[d];
    half8 w0 = *(const half8*)(wsh + OFF_F3 + (wv * 2 + 0) * 512 + lane * 8);
    half8 w1 = *(const half8*)(wsh + OFF_F3 + (wv * 2 + 1) * 512 + lane * 8);
    f32x4 acc[4] = {{0, 0, 0, 0}, {0, 0, 0, 0}, {0, 0, 0, 0}, {0, 0, 0, 0}};
#pragma unroll
    for (int mt = 0; mt < 4; ++mt) {
      half8 a0 = *(const half8*)&xA[xidx(mt * 16 + c16, quad * 8)];
      half8 a1 = *(const half8*)&xA[xidx(mt * 16 + c16, 32 + quad * 8)];
      acc[mt] = __builtin_amdgcn_mfma_f32_16x16x32_f16(a0, w0, acc[mt], 0, 0, 0);
      acc[mt] = __builtin_amdgcn_mfma_f32_16x16x32_f16(a1, w1, acc[mt], 0, 0, 0);
    }
#pragma unroll
    for (int mt = 0; mt < 4; ++mt)
#pragma unroll
      for (int r = 0; r < 4; ++r)
        hbuf[hidx(mt * 16 + quad * 4 + r, d)] = (hf)fmaxf(acc[mt][r] + b3v, 0.f);
  }
  __syncthreads();

  // fc4
  {
    float b4v = fc4_b[d];
    half8 w4[4];
#pragma unroll
    for (int ks = 0; ks < 4; ++ks)
      w4[ks] = *(const half8*)(wsh + OFF_F4 + (wv * 4 + ks) * 512 + lane * 8);
    f32x4 acc[4] = {{0, 0, 0, 0}, {0, 0, 0, 0}, {0, 0, 0, 0}, {0, 0, 0, 0}};
#pragma unroll
    for (int mt = 0; mt < 4; ++mt)
#pragma unroll
      for (int ks = 0; ks < 4; ++ks) {
        half8 a = *(const half8*)&hbuf[hidx(mt * 16 + c16, ks * 32 + quad * 8)];
        acc[mt] = __builtin_amdgcn_mfma_f32_16x16x32_f16(a, w4[ks], acc[mt], 0, 0, 0);
      }
    __syncthreads();
#pragma unroll
    for (int mt = 0; mt < 4; ++mt)
#pragma unroll
      for (int r = 0; r < 4; ++r)
        hbuf[hidx(mt * 16 + quad * 4 + r, d)] = (hf)(acc[mt][r] + b4v);
  }
  __syncthreads();

  // xW: per orig-gate g, store into pos {0,1,3,4,2,5}[g] of the 6-group
  half8 af[4][4];
#pragma unroll
  for (int mt = 0; mt < 4; ++mt)
#pragma unroll
    for (int ks = 0; ks < 4; ++ks)
      af[mt][ks] = *(const half8*)&hbuf[hidx(mt * 16 + c16, ks * 32 + quad * 8)];

  for (int cls = 0; cls < 2; ++cls) {
    for (int g = 0; g < 6; ++g) {
      int pos = (g < 2) ? g : (g < 4 ? g + 1 : (g == 4 ? 2 : 5));
      half8 wf[4];
#pragma unroll
      for (int ks = 0; ks < 4; ++ks)
        wf[ks] = *(const half8*)(wsh + OFF_WX + (((cls * 6 + g) * 8 + wv) * 4 + ks) * 512 + lane * 8);
      float bv = B_enc[cls * 768 + g * 128 + d];
#pragma unroll
      for (int mt = 0; mt < 4; ++mt) {
        f32x4 acc = {0.f, 0.f, 0.f, 0.f};
#pragma unroll
        for (int ks = 0; ks < 4; ++ks)
          acc = __builtin_amdgcn_mfma_f32_16x16x32_f16(af[mt][ks], wf[ks], acc, 0, 0, 0);
#pragma unroll
        for (int r = 0; r < 4; ++r) {
          int row = mt * 16 + quad * 4 + r;
          xout[row * 768 + d * 6 + pos] = (hf)(acc[r] + actf[row] * bv);
        }
      }
    }
    __syncthreads();  // xout complete for this class
    {
      const int* src = (const int*)xout;
      int* dst = (int*)(xWb + (((size_t)cls * 64 + bn) * 192 + l0) * 768);
#pragma unroll
      for (int i = 0; i < 12; ++i) {
        int base = (t + i * 512) * 4;
        *(int4v*)&dst[base] = *(const int4v*)&src[base];
      }
    }
    __syncthreads();
  }
}

// x-gate prefetch: unit u = t + i*1024; row units u<1536, col units >=1536
__device__ __forceinline__ void xpre(const hf* __restrict__ xg, int t, int sN,
                                     unsigned* pa, unsigned* pb) {
#pragma unroll
  for (int i = 0; i < 3; ++i) {
    int u = t + (i << 10);
    int colf = u >= 1536;
    int q = colf ? u - 1536 : u;
    int c = q >> 7, dd = q & 127;
    int rr = sN - c;
    unsigned a = 0, b = 0;
    if (rr >= 0 && rr < 16) {
      const hf* p = xg + (size_t)(rr * 12 + c) * 768 + dd * 6;
      if (colf) {  // pos 3 (ushort), pos 4,5 (dword)
        a = (unsigned)*(const unsigned short*)(p + 3);
        b = *(const unsigned*)(p + 4);
      } else {     // pos 0,1 (dword), pos 2 (ushort)
        a = *(const unsigned*)p;
        b = (unsigned)*(const unsigned short*)(p + 2);
      }
    }
    pa[i] = a;
    pb[i] = b;
  }
}
__device__ __forceinline__ float lo16f(unsigned v) {
  return (float)__builtin_bit_cast(half2v, v)[0];
}
__device__ __forceinline__ float hi16f(unsigned v) {
  return (float)__builtin_bit_cast(half2v, v)[1];
}

// ---- kernel 3: recurrence. 1024 thr, 16 waves (4/SIMD); 16 reg-frags (=64 AGPR) +
//      8 LDS frags per wave; single-buffer A; fp16 gate-planes; no spill ----
__global__ __launch_bounds__(1024) __attribute__((amdgpu_waves_per_eu(4, 4))) void witran(
    const hf* __restrict__ wsh, const float* __restrict__ fc1_w, const float* __restrict__ fc1_b,
    const float* __restrict__ fc2_w, const float* __restrict__ fc2_b,
    const hf* __restrict__ xWb, float* __restrict__ out) {
  const int cls = blockIdx.x & 1, bn = blockIdx.x >> 1;
  const int t = threadIdx.x, lane = t & 63, wv = t >> 6;  // wv 0..15
  const int c16 = lane & 15, quad = lane >> 4;
  const int d = (wv & 7) * 16 + c16;
  const int goff = (wv < 8) ? 0 : 3;

  __shared__ __attribute__((aligned(16))) hf wlds[16 * 4096];  // 8 frags/wave (j=2, all ks)
  __shared__ __attribute__((aligned(16))) hf A[4096];          // single buffer
  __shared__ hf g16[6 * 12 * CST];                             // gate planes, padded
  __shared__ float red[128];

  for (int i = t; i < 2048; i += 1024) ((int*)A)[i] = 0;

  // weights: j=0,1 (16 frags = 64 regs, AGPR-exact); j=2 -> per-wave LDS
  half8 wr[2][8];
  {
    const hf* wb = wsh + (((size_t)(cls * 16 + wv) * 3) * 8) * 512 + lane * 8;
#pragma unroll
    for (int ks = 0; ks < 8; ++ks) {
      wr[0][ks] = *(const half8*)(wb + ks * 512);
      wr[1][ks] = *(const half8*)(wb + (8 + ks) * 512);
    }
#pragma unroll
    for (int f = 0; f < 8; ++f)
      *(half8*)&wlds[wv * 4096 + f * 512 + lane * 8] = *(const half8*)(wb + (16 + f) * 512);
  }

  const hf* xg = xWb + ((size_t)cls * 64 + bn) * 192 * 768;

  unsigned pa[3], pb[3];
  xpre(xg, t, 0, pa, pb);
  __syncthreads();  // A zero + wlds visible

  for (int s = 0; s < Steps; ++s) {
    // ---- GEMM: own gate-triple, full K=256 (reads A only) ----
    f32x4 a0 = {0, 0, 0, 0}, a1 = a0, a2 = a0;
#pragma unroll
    for (int ks = 0; ks < 8; ++ks) {
      half8 av = *(const half8*)&A[aidx(c16, ks * 32 + quad * 8)];
      a0 = __builtin_amdgcn_mfma_f32_16x16x32_f16(av, wr[0][ks], a0, 0, 0, 0);
      a1 = __builtin_amdgcn_mfma_f32_16x16x32_f16(av, wr[1][ks], a1, 0, 0, 0);
      half8 w2 = *(const half8*)&wlds[wv * 4096 + ks * 512 + lane * 8];
      a2 = __builtin_amdgcn_mfma_f32_16x16x32_f16(av, w2, a2, 0, 0, 0);
    }
    // spill gate-triple to fp16 planes (rows 0..11 only)
    if (quad < 3) {
#pragma unroll
      for (int r = 0; r < 4; ++r) {
        int base = (quad * 4 + r) * CST + d;
        g16[(goff + 0) * 12 * CST + base] = (hf)a0[r];
        g16[(goff + 1) * 12 * CST + base] = (hf)a1[r];
        g16[(goff + 2) * 12 * CST + base] = (hf)a2[r];
      }
    }
    // read old h for own units BEFORE any update write (single-buffer WAR)
    float hold[3];
#pragma unroll
    for (int i = 0; i < 3; ++i) {
      int u = t + (i << 10);
      int colf = u >= 1536;
      int q = colf ? u - 1536 : u;
      int c = q >> 7, dd = q & 127;
      hold[i] = (float)A[aidx(c, colf ? 128 + dd : dd)];
    }
    __syncthreads();  // #1: g16 complete; all old-A reads done

    // ---- update: 3 h-units per lane; skip inactive slices ----
#pragma unroll
    for (int i = 0; i < 3; ++i) {
      int u = t + (i << 10);
      int colf = u >= 1536;
      int q = colf ? u - 1536 : u;
      int c = q >> 7, dd = q & 127;
      if (c <= s) {
        int base = c * CST + dd;
        int po = colf ? 3 : 0;
        float gu = (float)g16[(po + 0) * 12 * CST + base];
        float go = (float)g16[(po + 1) * 12 * CST + base];
        float gi = (float)g16[(po + 2) * 12 * CST + base];
        float xu, xo, xi;
        if (colf) {
          xu = lo16f(pa[i]); xo = lo16f(pb[i]); xi = hi16f(pb[i]);
        } else {
          xu = lo16f(pa[i]); xo = hi16f(pa[i]); xi = lo16f(pb[i]);
        }
        float uu = sigmoidf_(gu + xu), oo = sigmoidf_(go + xo), ii = tanh_(gi + xi);
        float h = tanh_((1.f - uu) * hold[i] + uu * ii) * oo;
        if (colf) {
          int c2 = (c == 11) ? 0 : c + 1;  // roll: new h_col[c] feeds slice c+1
          A[aidx(c2, 128 + dd)] = (hf)h;
        } else {
          A[aidx(c, dd)] = (hf)h;
        }
      }
    }
    // prefetch next step's x-gates (after last pa/pb use; hides across barrier+GEMM)
    xpre(xg, t, s + 1, pa, pb);
    __syncthreads();  // #2: A complete for next step
  }

  // ---- epilogue: h_row[11] at A[11][0:128); rolled h_col[11] at A[0][128:256) ----
  if (t < 128) {
    float hr = (float)A[aidx(11, t)];
    float hc = (float)A[aidx(0, 128 + t)];
    red[t] = 0.5f * (hc * fc1_w[cls * 128 + t] + hr * fc2_w[cls * 128 + t]);
  }
  __syncthreads();
  if (t == 0) {
    float sum = 0.f;
    for (int i = 0; i < 128; ++i) sum += red[i];
    out[bn * 2 + cls] = sum + 0.5f * (fc1_b[cls] + fc2_b[cls]);
  }
}

extern "C" void kernel_launch(void* const* d_in, const int* in_sizes, int n_in,
                              void* d_out, int out_size, void* d_ws, size_t ws_size,
                              hipStream_t stream) {
  const float* x = (const float*)d_in[0];
  // d_in[1] = pad_mask: unused by the reference
  const float* fc3_w = (const float*)d_in[2];
  const float* fc3_b = (const float*)d_in[3];
  const float* fc4_w = (const float*)d_in[4];
  const float* fc4_b = (const float*)d_in[5];
  const float* W_enc = (const float*)d_in[6];
  const float* B_enc = (const float*)d_in[7];
  const float* fc1_w = (const float*)d_in[8];
  const float* fc1_b = (const float*)d_in[9];
  const float* fc2_w = (const float*)d_in[10];
  const float* fc2_b = (const float*)d_in[11];
  float* out = (float*)d_out;

  hf* wsh = (hf*)d_ws;        // frag tables 1,228,800 B
  hf* xWb = wsh + OFF_XW;     // 37,748,736 B ; total 38,977,536 B

  prep<<<dim3(1200), dim3(512), 0, stream>>>(fc3_w, fc4_w, W_enc, wsh);
  prelude<<<dim3(192), dim3(512), 0, stream>>>(x, fc3_b, fc4_b, B_enc, wsh, xWb);
  witran<<<dim3(128), dim3(1024), 0, stream>>>(wsh, fc1_w, fc1_b, fc2_w, fc2_b, xWb, out);
}